// Round 11
// baseline (263.710 us; speedup 1.0000x reference)
//
#include <hip/hip_runtime.h>
#include <math.h>

// Damping: B=32768, N=64, H=256, OFF=2016
//   diag: x -> tanh(Wd1) -> tanh(Wd2) -> Wdo   (64 per sample)
//   off : x -> tanh(Wo1) -> tanh(Wo2) -> Woo   (2016 per sample, strict lower tri)
//   out = L (L^T x0), L diag = xd, L[i][j](j<i) = z[i(i-1)/2+j]
//
// z layout: plain row-padded packed triangle per sample: z[s][2112], row i at
// rs(i) = tri(i) + 6*(i>>2) + adj[i&3], padded to x4 with zeros (written by gemm_z).

#define B_TOT 32768
#define NDIM  64
#define HDIM  256
#define OFFD  2016
#define QS    8192
#define ZROW  2112                  // padded triangle length per sample
#define GRP_BYTES (32 * ZROW * 2)   // 135168 B per 32-sample group

typedef __bf16 bf16x8 __attribute__((ext_vector_type(8)));
typedef float  f32x4  __attribute__((ext_vector_type(4)));

__device__ __forceinline__ float fast_tanh(float x) {
  float e = __expf(2.f * x);
  return 1.f - 2.f * __builtin_amdgcn_rcpf(e + 1.f);
}
__device__ __forceinline__ float lane_bcast(float v, int l) {
  return __uint_as_float(__builtin_amdgcn_readlane(__float_as_uint(v), l));
}
__device__ __forceinline__ float bf_lo(unsigned w) { return __uint_as_float(w << 16); }
__device__ __forceinline__ float bf_hi(unsigned w) { return __uint_as_float(w & 0xffff0000u); }

__device__ __forceinline__ void gload_lds16(const void* g, void* l) {
  __builtin_amdgcn_global_load_lds(
      (const __attribute__((address_space(1))) unsigned*)g,
      (__attribute__((address_space(3))) unsigned*)l, 16, 0, 0);
}

#define MFMA(A, B, C) __builtin_amdgcn_mfma_f32_16x16x32_bf16((A), (B), (C), 0, 0, 0)
#define SB0() __builtin_amdgcn_sched_barrier(0)
// XOR-swizzled 16B-granule byte offset within a row (low 3 bits of granule)
#define GOFF(g, row) (((((g) & ~7) | (((g) & 7) ^ ((row) & 7)))) << 4)

// ---------------- weight cast (f32 -> bf16) + Woob pad zero-fill ----------------
__device__ __forceinline__ void cast_range(const float* __restrict__ s,
                                           __bf16* __restrict__ d, int n) {
  int i = blockIdx.x * blockDim.x + threadIdx.x;
  const int stride = gridDim.x * blockDim.x;
  for (; i < n; i += stride) d[i] = (__bf16)s[i];
}
__global__ __launch_bounds__(256) void cast_all_kernel(
    const float* s0, __bf16* d0, int n0, const float* s1, __bf16* d1, int n1,
    const float* s2, __bf16* d2, int n2, const float* s3, __bf16* d3, int n3,
    const float* s4, __bf16* d4, int n4, const float* s5, __bf16* d5, int n5,
    __bf16* d6, int n6) {
  cast_range(s0, d0, n0); cast_range(s1, d1, n1); cast_range(s2, d2, n2);
  cast_range(s3, d3, n3); cast_range(s4, d4, n4); cast_range(s5, d5, n5);
  int i = blockIdx.x * blockDim.x + threadIdx.x;
  const int stride = gridDim.x * blockDim.x;
  for (; i < n6; i += stride) d6[i] = (__bf16)0.f;
}

__device__ __forceinline__ bf16x8 cvt8(const float* __restrict__ p) {
  const float4 u = *(const float4*)p;
  const float4 v = *(const float4*)(p + 4);
  bf16x8 r;
  r[0] = (__bf16)u.x; r[1] = (__bf16)u.y; r[2] = (__bf16)u.z; r[3] = (__bf16)u.w;
  r[4] = (__bf16)v.x; r[5] = (__bf16)v.y; r[6] = (__bf16)v.z; r[7] = (__bf16)v.w;
  return r;
}

// ---------------- K1: all-LDS trunk, 64 samples/WG, 3-deep counted pipeline -----
// Wcat chunks (16KB): [0,4)=W1(Wd1|Wo1,128B rows) [4,12)=Wo2 [12,20)=Wd2 [20,22)=Wdo
// LDS: xa 8KB | act 64KB (h1=g0..31, g1/h2=g32..63) | wbuf 3x16KB
#define TRUNK_SMEM (8192 + 65536 + 49152)
#define NCHUNK 22

__device__ __forceinline__ void stage_chunk(const char* Wcat, char* wb,
                                            int c, int buf, int wave) {
  const char* base = Wcat + (size_t)c * 16384;
  char* dst = wb + buf * 16384;
  const int lane = threadIdx.x & 63;
  const int s0 = wave * 64 + lane;
  const int s1 = s0 + 512;
  if (c < 4) {  // 128-byte rows (8 granules)
    const int r0 = s0 >> 3, q0 = (s0 & 7) ^ (r0 & 7);
    gload_lds16(base + r0 * 128 + (q0 << 4), dst + wave * 1024);
    const int r1 = s1 >> 3, q1 = (s1 & 7) ^ (r1 & 7);
    gload_lds16(base + r1 * 128 + (q1 << 4), dst + (wave + 8) * 1024);
  } else {      // 512-byte rows (32 granules)
    const int r0 = s0 >> 5, g0 = s0 & 31;
    const int q0 = (g0 & 24) | ((g0 & 7) ^ (r0 & 7));
    gload_lds16(base + r0 * 512 + (q0 << 4), dst + wave * 1024);
    const int r1 = s1 >> 5, g1 = s1 & 31;
    const int q1 = (g1 & 24) | ((g1 & 7) ^ (r1 & 7));
    gload_lds16(base + r1 * 512 + (q1 << 4), dst + (wave + 8) * 1024);
  }
}

// counted-vmcnt chunk tail: certify stage(gc+1) at the barrier; keep stage(gc+2)
// in flight. Raw s_barrier (no compiler vmcnt(0) drain).
#define CHUNK_TAIL(GC)                                                     \
  if ((GC) + 2 < NCHUNK) stage_chunk(Wc, wb, (GC) + 2, ((GC) + 2) % 3, wave); \
  asm volatile("s_waitcnt lgkmcnt(0)" ::: "memory");                       \
  if ((GC) + 2 < NCHUNK) {                                                 \
    asm volatile("s_waitcnt vmcnt(2)" ::: "memory");                       \
  } else {                                                                 \
    asm volatile("s_waitcnt vmcnt(0)" ::: "memory");                       \
  }                                                                        \
  __builtin_amdgcn_s_barrier();                                            \
  asm volatile("" ::: "memory");

__global__ __launch_bounds__(512, 2) void trunk_kernel(
    const float* __restrict__ x, const __bf16* __restrict__ Wcat,
    const float* __restrict__ bd1, const float* __restrict__ bo1,
    const float* __restrict__ bd2, const float* __restrict__ bo2,
    const float* __restrict__ bdo,
    __bf16* __restrict__ g2, float* __restrict__ xd) {
  extern __shared__ char smem[];
  char* xa  = smem;            // 8 KB
  char* act = smem + 8192;     // 64 KB
  char* wb  = smem + 73728;    // 48 KB (3 bufs)
  const char* Wc = (const char*)Wcat;

  const int tid = threadIdx.x;
  const int wave = tid >> 6, lane = tid & 63;
  const int lr = lane & 15, lg = lane >> 4;
  const int sb = blockIdx.x * 64;

  // preload all biases (keeps vmcnt clean inside the pipeline)
  float bvL1[4], bvo[8], bvd[8], bvl3[2];
#pragma unroll
  for (int cc = 0; cc < 4; ++cc) {
    const int ch = cc * 128 + wave * 16 + lr;
    bvL1[cc] = (ch < 256) ? bd1[ch] : bo1[ch - 256];
  }
#pragma unroll
  for (int cc = 0; cc < 8; ++cc) {
    const int ch = cc * 32 + (wave & 1) * 16 + lr;
    bvo[cc] = bo2[ch];
    bvd[cc] = bd2[ch];
  }
#pragma unroll
  for (int cc = 0; cc < 2; ++cc)
    bvl3[cc] = bdo[cc * 32 + (wave & 1) * 16 + lr];

  // stage x -> xa (bf16, swizzled)
  {
    const int s = tid >> 3, g = tid & 7;
    const bf16x8 v = cvt8(x + (size_t)(sb + s) * 64 + g * 8);
    *(bf16x8*)(xa + s * 128 + GOFF(g, s)) = v;
  }
  stage_chunk(Wc, wb, 0, 0, wave);
  stage_chunk(Wc, wb, 1, 1, wave);
  __syncthreads();  // full drain: buf0, buf1, xa certified

  // ---- L1: chunks 0..3 (128 ch each), wave = n-tile ----
#pragma unroll
  for (int cc = 0; cc < 4; ++cc) {
    const int gc = cc;
    const char* wbp = wb + (gc % 3) * 16384;
    const int brow = wave * 16 + lr;
    const bf16x8 b0 = *(const bf16x8*)(wbp + brow * 128 + GOFF(lg, brow));
    const bf16x8 b1 = *(const bf16x8*)(wbp + brow * 128 + GOFF(4 + lg, brow));
    const int ch = cc * 128 + brow;
    const float bv = bvL1[cc];
#pragma unroll
    for (int m = 0; m < 4; ++m) {
      const int arow = m * 16 + lr;
      const bf16x8 a0 = *(const bf16x8*)(xa + arow * 128 + GOFF(lg, arow));
      const bf16x8 a1 = *(const bf16x8*)(xa + arow * 128 + GOFF(4 + lg, arow));
      f32x4 acc = {0.f, 0.f, 0.f, 0.f};
      acc = MFMA(a0, b0, acc);
      acc = MFMA(a1, b1, acc);
#pragma unroll
      for (int r = 0; r < 4; ++r) {
        const int s = m * 16 + lg * 4 + r;
        *(__bf16*)(act + s * 1024 + GOFF(ch >> 3, s) + (ch & 7) * 2) =
            (__bf16)fast_tanh(acc[r] + bv);
      }
    }
    CHUNK_TAIL(gc)
  }

  // ---- L2o: chunks 4..11 (Wo2); reads g1 (g32..63) -> g2 global ----
#pragma unroll
  for (int cc = 0; cc < 8; ++cc) {
    const int gc = 4 + cc;
    const char* wbp = wb + (gc % 3) * 16384;
    const int m = wave >> 1, n = wave & 1;
    const int ch = cc * 32 + n * 16 + lr;
    const int brow = n * 16 + lr;
    const int arow = m * 16 + lr;
    f32x4 acc = {0.f, 0.f, 0.f, 0.f};
#pragma unroll
    for (int ks = 0; ks < 8; ++ks) {
      const int g = 32 + ks * 4 + lg;
      const bf16x8 a = *(const bf16x8*)(act + arow * 1024 + GOFF(g, arow));
      const bf16x8 b = *(const bf16x8*)(wbp + brow * 512 + GOFF(ks * 4 + lg, brow));
      acc = MFMA(a, b, acc);
    }
    const float bv = bvo[cc];
#pragma unroll
    for (int r = 0; r < 4; ++r) {
      const int s = m * 16 + lg * 4 + r;
      g2[(size_t)(sb + s) * 256 + ch] = (__bf16)fast_tanh(acc[r] + bv);
    }
    CHUNK_TAIL(gc)
  }

  // ---- L2d: chunks 12..19 (Wd2); reads h1 (g0..31) -> h2 into g32..63 ----
#pragma unroll
  for (int cc = 0; cc < 8; ++cc) {
    const int gc = 12 + cc;
    const char* wbp = wb + (gc % 3) * 16384;
    const int m = wave >> 1, n = wave & 1;
    const int ch = cc * 32 + n * 16 + lr;
    const int brow = n * 16 + lr;
    const int arow = m * 16 + lr;
    f32x4 acc = {0.f, 0.f, 0.f, 0.f};
#pragma unroll
    for (int ks = 0; ks < 8; ++ks) {
      const int g = ks * 4 + lg;
      const bf16x8 a = *(const bf16x8*)(act + arow * 1024 + GOFF(g, arow));
      const bf16x8 b = *(const bf16x8*)(wbp + brow * 512 + GOFF(g, brow));
      acc = MFMA(a, b, acc);
    }
    const float bv = bvd[cc];
#pragma unroll
    for (int r = 0; r < 4; ++r) {
      const int s = m * 16 + lg * 4 + r;
      const int gd = 32 | (ch >> 3);
      *(__bf16*)(act + s * 1024 + GOFF(gd, s) + (ch & 7) * 2) =
          (__bf16)fast_tanh(acc[r] + bv);
    }
    CHUNK_TAIL(gc)
  }

  // ---- L3: chunks 20..21 (Wdo); reads h2 (g32..63) -> xd global f32 ----
#pragma unroll
  for (int cc = 0; cc < 2; ++cc) {
    const int gc = 20 + cc;
    const char* wbp = wb + (gc % 3) * 16384;
    const int m = wave >> 1, n = wave & 1;
    const int ch = cc * 32 + n * 16 + lr;
    const int brow = n * 16 + lr;
    const int arow = m * 16 + lr;
    f32x4 acc = {0.f, 0.f, 0.f, 0.f};
#pragma unroll
    for (int ks = 0; ks < 8; ++ks) {
      const int g = 32 + ks * 4 + lg;
      const bf16x8 a = *(const bf16x8*)(act + arow * 1024 + GOFF(g, arow));
      const bf16x8 b = *(const bf16x8*)(wbp + brow * 512 + GOFF(ks * 4 + lg, brow));
      acc = MFMA(a, b, acc);
    }
    const float bv = bvl3[cc];
#pragma unroll
    for (int r = 0; r < 4; ++r) {
      const int s = m * 16 + lg * 4 + r;
      xd[(size_t)(sb + s) * 64 + ch] = acc[r] + bv;
    }
    if (cc == 0) { CHUNK_TAIL(gc) }
  }
}

// ---------------- gemm_z: z[8192 x 2016] = G @ Woo^T + boo  (per quarter) -------
// 256x256 tiles, BK=64, 8 waves; double-buffered global_load_lds staging.
// Epilogue: contiguous scalar stores into row-padded packed triangle + pad zeros.
#define TILE_BYTES 32768
#define GEMM_SMEM  131072

__global__ __launch_bounds__(512, 2) void gemm_z_kernel(
    const __bf16* __restrict__ g2q, const __bf16* __restrict__ Woob,
    const float* __restrict__ boo, __bf16* __restrict__ zq) {
  extern __shared__ char gsm[];
  const int tid = threadIdx.x;
  const int wave = tid >> 6, lane = tid & 63;
  const int lr = lane & 15, lg = lane >> 4;
  const int bm = blockIdx.x & 31, bn = blockIdx.x >> 5;
  const int wr = wave >> 2, wc = wave & 3;
  const int srl = lane >> 3;
  const int sch = lane & 7;

#define STAGE(BUF, KT)                                                          \
  {                                                                             \
    _Pragma("unroll")                                                           \
    for (int j = 0; j < 4; ++j) {                                               \
      const int row = wave * 32 + j * 8 + srl;                                  \
      const int ka = (KT) * 64 + ((sch ^ (row & 7)) << 3);                      \
      gload_lds16(g2q + (size_t)(bm * 256 + row) * 256 + ka,                    \
                  gsm + (BUF) * TILE_BYTES + wave * 4096 + j * 1024);           \
      gload_lds16(Woob + (size_t)(bn * 256 + row) * 256 + ka,                   \
                  gsm + 65536 + (BUF) * TILE_BYTES + wave * 4096 + j * 1024);   \
    }                                                                           \
  }

  f32x4 acc[8][4];
#pragma unroll
  for (int i = 0; i < 8; ++i)
#pragma unroll
    for (int j = 0; j < 4; ++j) acc[i][j] = (f32x4){0.f, 0.f, 0.f, 0.f};

  STAGE(0, 0)
  __syncthreads();
#pragma unroll
  for (int kt = 0; kt < 4; ++kt) {
    if (kt < 3) STAGE((kt + 1) & 1, kt + 1)
    const __bf16* Ab = (const __bf16*)(gsm + (kt & 1) * TILE_BYTES);
    const __bf16* Bb = (const __bf16*)(gsm + 65536 + (kt & 1) * TILE_BYTES);
#pragma unroll
    for (int ks = 0; ks < 2; ++ks) {
      const int cc = ((ks * 4 + lg) ^ (lr & 7)) << 3;
      bf16x8 af[8];
#pragma unroll
      for (int fr = 0; fr < 8; ++fr)
        af[fr] = *(const bf16x8*)(Ab + (wr * 128 + fr * 16 + lr) * 64 + cc);
      bf16x8 bfr[4];
#pragma unroll
      for (int fc = 0; fc < 4; ++fc)
        bfr[fc] = *(const bf16x8*)(Bb + (wc * 64 + fc * 16 + lr) * 64 + cc);
#pragma unroll
      for (int fr = 0; fr < 8; ++fr)
#pragma unroll
        for (int fc = 0; fc < 4; ++fc)
          acc[fr][fc] = MFMA(af[fr], bfr[fc], acc[fr][fc]);
    }
    if (kt < 3) __syncthreads();
  }

  // epilogue: contiguous scalar stores into z[s][ZROW]; lastcol lanes zero pads
#pragma unroll
  for (int fc = 0; fc < 4; ++fc) {
    const int col = bn * 256 + wc * 64 + fc * 16 + lr;
    if (col < OFFD) {
      const float sq = sqrtf((float)(1 + 8 * col));
      const int i = (int)((1.f + sq) * 0.5f);
      const int tri = (i * (i - 1)) >> 1;
      const int r3i = i & 3;
      const int offv =
          tri + 6 * (i >> 2) + ((r3i == 2) ? 3 : (r3i == 3) ? 5 : 0) + (col - tri);
      const float bv = boo[col];
      const int pc = (4 - r3i) & 3;
      const bool lastcol = (col == tri + i - 1);
#pragma unroll
      for (int fr = 0; fr < 8; ++fr) {
#pragma unroll
        for (int r = 0; r < 4; ++r) {
          const int srow = bm * 256 + wr * 128 + fr * 16 + lg * 4 + r;
          __bf16* p = zq + (size_t)srow * ZROW + offv;
          *p = (__bf16)(acc[fr][fc][r] + bv);
          if (lastcol) {
#pragma unroll
            for (int d = 0; d < 3; ++d)
              if (d < pc) p[1 + d] = (__bf16)0.f;
          }
        }
      }
    }
  }
}

// ---------------- apply: wave-local stage of 2 samples + two triangular passes --
#define APPLY_SMEM (GRP_BYTES + 8192)
__global__ __launch_bounds__(1024) void apply_kernel(
    const __bf16* __restrict__ zq, const float* __restrict__ xd,
    const float* __restrict__ x0, float* __restrict__ out, int s0base) {
  extern __shared__ char smem[];
  __bf16* ztb = (__bf16*)smem;             // [32 samples][ZROW]
  float* ys2 = (float*)(smem + GRP_BYTES); // [wave][2][64]

  const int tid = threadIdx.x;
  const int wave = tid >> 6, lane = tid & 63;
  const int sb = s0base + blockIdx.x * 32;
  const int s0 = wave * 2, s1 = s0 + 1;

  const float x0vA = x0[(size_t)(sb + s0) * 64 + lane];
  const float x0vB = x0[(size_t)(sb + s1) * 64 + lane];
  const float xdA = xd[(size_t)(sb + s0) * 64 + lane];
  const float xdB = xd[(size_t)(sb + s1) * 64 + lane];

  // stage this wave's 2 samples (8448 B), wave-local
  {
    const char* src = (const char*)zq + (size_t)blockIdx.x * GRP_BYTES + wave * 8448;
    char* dst = smem + wave * 8448;
#pragma unroll
    for (int j = 0; j < 8; ++j)
      gload_lds16(src + j * 1024 + lane * 16, dst + j * 1024);
    if (lane < 16) gload_lds16(src + 8192 + lane * 16, dst + 8192);
  }
  asm volatile("s_waitcnt vmcnt(0)" ::: "memory");
  SB0();

  const __bf16* zsA = ztb + wave * 2 * ZROW;
  const __bf16* zsB = zsA + ZROW;

  // pass 1: y_j = xd_j x0_j + sum_{k>j} z[k][j] x0_k
  float yA = xdA * x0vA, yB = xdB * x0vB;
  int rs = 0;
#pragma unroll
  for (int k = 1; k < 64; ++k) {
    const float zA = (float)zsA[rs + lane];
    const float zB = (float)zsB[rs + lane];
    const float xkA = lane_bcast(x0vA, k);
    const float xkB = lane_bcast(x0vB, k);
    const bool mv = lane < k;
    yA += mv ? zA * xkA : 0.f;
    yB += mv ? zB * xkB : 0.f;
    rs += (k + 3) & ~3;
  }

  float* ypA = ys2 + wave * 128;
  float* ypB = ypA + 64;
  ypA[lane] = yA;
  ypB[lane] = yB;
  asm volatile("s_waitcnt lgkmcnt(0)" ::: "memory");
  SB0();

  // pass 2: D_i = xd_i y_i + sum_{j<i} z[i][j] y_j  (zero pads absorb tail)
  float DA = xdA * yA, DB = xdB * yB;
  {
    const int r3 = lane & 3;
    const int rsi = ((lane * (lane - 1)) >> 1) + 6 * (lane >> 2) +
                    ((r3 == 2) ? 3 : (r3 == 3) ? 5 : 0);
    const int cmax = (lane + 3) >> 2;
    const char* zrA = (const char*)zsA + rsi * 2;
    const char* zrB = (const char*)zsB + rsi * 2;
#pragma unroll 4
    for (int c = 0; c < cmax; ++c) {
      const uint2 wA = *(const uint2*)(zrA + c * 8);
      const uint2 wB = *(const uint2*)(zrB + c * 8);
      const float4 u = *(const float4*)(ypA + c * 4);
      const float4 v = *(const float4*)(ypB + c * 4);
      DA += bf_lo(wA.x) * u.x + bf_hi(wA.x) * u.y + bf_lo(wA.y) * u.z + bf_hi(wA.y) * u.w;
      DB += bf_lo(wB.x) * v.x + bf_hi(wB.x) * v.y + bf_lo(wB.y) * v.z + bf_hi(wB.y) * v.w;
    }
  }
  out[(size_t)(sb + s0) * 64 + lane] = DA;
  out[(size_t)(sb + s1) * 64 + lane] = DB;
}

// ---------------- launch ----------------
extern "C" void kernel_launch(void* const* d_in, const int* in_sizes, int n_in,
                              void* d_out, int out_size, void* d_ws, size_t ws_size,
                              hipStream_t stream) {
  const float* x   = (const float*)d_in[0];
  const float* Wd1 = (const float*)d_in[1];
  const float* bd1 = (const float*)d_in[2];
  const float* Wd2 = (const float*)d_in[3];
  const float* bd2 = (const float*)d_in[4];
  const float* Wdo = (const float*)d_in[5];
  const float* bdo = (const float*)d_in[6];
  const float* Wo1 = (const float*)d_in[7];
  const float* bo1 = (const float*)d_in[8];
  const float* Wo2 = (const float*)d_in[9];
  const float* bo2 = (const float*)d_in[10];
  const float* Woo = (const float*)d_in[11];
  const float* boo = (const float*)d_in[12];
  float* out = (float*)d_out;

  char* ws = (char*)d_ws;
  // Wcat layout (bf16 elems): Wd1@0, Wo1@16384, Wo2@32768, Wd2@98304, Wdo@163840
  __bf16* Wcat = (__bf16*)(ws + 0);          //   360448 B
  __bf16* Woob = (__bf16*)(ws + 360448);     //  1048576 B (2048 rows, zero-padded)
  __bf16* g2   = (__bf16*)(ws + 1409024);    // 16777216 B
  float*  xdp  = (float*)(ws + 18186240);    //  8388608 B
  __bf16* zq   = (__bf16*)(ws + 26574848);   // 34603008 B (one quarter, [8192][2112])

  cast_all_kernel<<<512, 256, 0, stream>>>(
      Wd1, Wcat, HDIM * NDIM,
      Wo1, Wcat + 16384, HDIM * NDIM,
      Wo2, Wcat + 32768, HDIM * HDIM,
      Wd2, Wcat + 98304, HDIM * HDIM,
      Wdo, Wcat + 163840, NDIM * HDIM,
      Woo, Woob, OFFD * HDIM,
      Woob + OFFD * HDIM, 32 * HDIM);

  hipFuncSetAttribute((const void*)trunk_kernel,
                      hipFuncAttributeMaxDynamicSharedMemorySize, TRUNK_SMEM);
  trunk_kernel<<<B_TOT / 64, 512, TRUNK_SMEM, stream>>>(
      x, Wcat, bd1, bo1, bd2, bo2, bdo, g2, xdp);

  hipFuncSetAttribute((const void*)gemm_z_kernel,
                      hipFuncAttributeMaxDynamicSharedMemorySize, GEMM_SMEM);
  hipFuncSetAttribute((const void*)apply_kernel,
                      hipFuncAttributeMaxDynamicSharedMemorySize, APPLY_SMEM);
  for (int q = 0; q < 4; ++q) {
    gemm_z_kernel<<<(QS / 256) * 8, 512, GEMM_SMEM, stream>>>(
        g2 + (size_t)q * QS * HDIM, Woob, boo, zq);
    apply_kernel<<<QS / 32, 1024, APPLY_SMEM, stream>>>(zq, xdp, x, out, q * QS);
  }
}

// Round 13
// 188.489 us; speedup vs baseline: 1.3991x; 1.3991x over previous
//
#include <hip/hip_runtime.h>
#include <math.h>

// Damping: B=32768, N=64, H=256, OFF=2016
//   diag: x -> tanh(Wd1) -> tanh(Wd2) -> Wdo   (64 per sample)
//   off : x -> tanh(Wo1) -> tanh(Wo2) -> Woo   (2016 per sample, strict lower tri)
//   out = L (L^T x0), L diag = xd, L[i][j](j<i) = z[i(i-1)/2+j]
//
// z path (round-10 proven): gemm_z 256x256-tile LDS-staged GEMM -> HBM in
// pair-interleaved padded-triangle groups of 32 samples -> apply (wave-local).

#define B_TOT 32768
#define NDIM  64
#define HDIM  256
#define OFFD  2016
#define QS    8192
#define GRP_UNITS 67584            // 16 pairs * 4224 bf16 units per 32-sample group
#define GRP_BYTES 135168

typedef __bf16 bf16x8 __attribute__((ext_vector_type(8)));
typedef float  f32x4  __attribute__((ext_vector_type(4)));

__device__ __forceinline__ float fast_tanh(float x) {
  float e = __expf(2.f * x);
  return 1.f - 2.f * __builtin_amdgcn_rcpf(e + 1.f);
}
__device__ __forceinline__ float lane_bcast(float v, int l) {
  return __uint_as_float(__builtin_amdgcn_readlane(__float_as_uint(v), l));
}
__device__ __forceinline__ float bf_lo(unsigned w) { return __uint_as_float(w << 16); }
__device__ __forceinline__ float bf_hi(unsigned w) { return __uint_as_float(w & 0xffff0000u); }
__device__ __forceinline__ unsigned bfbits(float f) {
  __bf16 h = (__bf16)f;
  return (unsigned)__builtin_bit_cast(unsigned short, h);
}

__device__ __forceinline__ void gload_lds16(const void* g, void* l) {
  __builtin_amdgcn_global_load_lds(
      (const __attribute__((address_space(1))) unsigned*)g,
      (__attribute__((address_space(3))) unsigned*)l, 16, 0, 0);
}

#define MFMA(A, B, C) __builtin_amdgcn_mfma_f32_16x16x32_bf16((A), (B), (C), 0, 0, 0)
#define SB0() __builtin_amdgcn_sched_barrier(0)
// XOR-swizzled 16B-granule byte offset within a row (low 3 bits of granule)
#define GOFF(g, row) (((((g) & ~7) | (((g) & 7) ^ ((row) & 7)))) << 4)

// ---------------- weight cast (f32 -> bf16) + Woob pad zero-fill ----------------
__device__ __forceinline__ void cast_range(const float* __restrict__ s,
                                           __bf16* __restrict__ d, int n) {
  int i = blockIdx.x * blockDim.x + threadIdx.x;
  const int stride = gridDim.x * blockDim.x;
  for (; i < n; i += stride) d[i] = (__bf16)s[i];
}
__global__ __launch_bounds__(256) void cast_all_kernel(
    const float* s0, __bf16* d0, int n0, const float* s1, __bf16* d1, int n1,
    const float* s2, __bf16* d2, int n2, const float* s3, __bf16* d3, int n3,
    const float* s4, __bf16* d4, int n4, const float* s5, __bf16* d5, int n5,
    __bf16* d6, int n6) {
  cast_range(s0, d0, n0); cast_range(s1, d1, n1); cast_range(s2, d2, n2);
  cast_range(s3, d3, n3); cast_range(s4, d4, n4); cast_range(s5, d5, n5);
  int i = blockIdx.x * blockDim.x + threadIdx.x;
  const int stride = gridDim.x * blockDim.x;
  for (; i < n6; i += stride) d6[i] = (__bf16)0.f;
}

__device__ __forceinline__ bf16x8 cvt8(const float* __restrict__ p) {
  const float4 u = *(const float4*)p;
  const float4 v = *(const float4*)(p + 4);
  bf16x8 r;
  r[0] = (__bf16)u.x; r[1] = (__bf16)u.y; r[2] = (__bf16)u.z; r[3] = (__bf16)u.w;
  r[4] = (__bf16)v.x; r[5] = (__bf16)v.y; r[6] = (__bf16)v.z; r[7] = (__bf16)v.w;
  return r;
}

// ---------------- shared trunk machinery: 64 samples/WG, 72KB LDS, 2 WG/CU ------
// LDS: xa 8KB | act 32KB (64 samples x 256 ch, swizzled granules) | wbuf 2x16KB
// Double-buffer discipline: stage chunk c+1 into buf (c+1)&1 while computing
// chunk c from buf c&1; __syncthreads() (drains vmcnt) certifies the stage.
#define TRK_SMEM (8192 + 32768 + 32768)

// stage one 16KB weight chunk; rows are 128B if c<2 else 512B
__device__ __forceinline__ void stage_chunk2(const char* wreg, char* wb,
                                             int c, int wave) {
  const char* base = wreg + (size_t)c * 16384;
  char* dst = wb + (c & 1) * 16384;
  const int lane = threadIdx.x & 63;
  const int s0 = wave * 64 + lane;
  const int s1 = s0 + 512;
  if (c < 2) {  // 128-byte rows (8 granules)
    const int r0 = s0 >> 3, q0 = (s0 & 7) ^ (r0 & 7);
    gload_lds16(base + r0 * 128 + (q0 << 4), dst + wave * 1024);
    const int r1 = s1 >> 3, q1 = (s1 & 7) ^ (r1 & 7);
    gload_lds16(base + r1 * 128 + (q1 << 4), dst + (wave + 8) * 1024);
  } else {      // 512-byte rows (32 granules)
    const int r0 = s0 >> 5, g0 = s0 & 31;
    const int q0 = (g0 & 24) | ((g0 & 7) ^ (r0 & 7));
    gload_lds16(base + r0 * 512 + (q0 << 4), dst + wave * 1024);
    const int r1 = s1 >> 5, g1 = s1 & 31;
    const int q1 = (g1 & 24) | ((g1 & 7) ^ (r1 & 7));
    gload_lds16(base + r1 * 512 + (q1 << 4), dst + (wave + 8) * 1024);
  }
}

// ---------------- off_trunk: x -> tanh(Wo1) -> tanh(Wo2) -> g2 ------------------
// chunks: 0-1 = Wo1 (128B rows), 2-9 = Wo2 (512B rows)
__global__ __launch_bounds__(512, 2) void off_trunk_kernel(
    const float* __restrict__ x, const __bf16* __restrict__ Wreg,
    const float* __restrict__ bo1, const float* __restrict__ bo2,
    __bf16* __restrict__ g2) {
  extern __shared__ char smem[];
  char* xa  = smem;            // 8 KB
  char* act = smem + 8192;     // 32 KB (g1)
  char* wb  = smem + 40960;    // 32 KB
  const char* Wc = (const char*)Wreg;

  const int tid = threadIdx.x;
  const int wave = tid >> 6, lane = tid & 63;
  const int lr = lane & 15, lg = lane >> 4;
  const int sb = blockIdx.x * 64;

  float bv1[2], bv2[8];
#pragma unroll
  for (int cc = 0; cc < 2; ++cc) bv1[cc] = bo1[cc * 128 + wave * 16 + lr];
#pragma unroll
  for (int cc = 0; cc < 8; ++cc) bv2[cc] = bo2[cc * 32 + (wave & 1) * 16 + lr];

  {
    const int s = tid >> 3, g = tid & 7;
    const bf16x8 v = cvt8(x + (size_t)(sb + s) * 64 + g * 8);
    *(bf16x8*)(xa + s * 128 + GOFF(g, s)) = v;
  }
  stage_chunk2(Wc, wb, 0, wave);
  __syncthreads();

  // L1o: chunks 0-1 (128 ch each); wave = n-tile
#pragma unroll
  for (int cc = 0; cc < 2; ++cc) {
    stage_chunk2(Wc, wb, cc + 1, wave);           // 1-ahead, alternate buffer
    const char* wbp = wb + (cc & 1) * 16384;
    const int brow = wave * 16 + lr;
    const bf16x8 b0 = *(const bf16x8*)(wbp + brow * 128 + GOFF(lg, brow));
    const bf16x8 b1 = *(const bf16x8*)(wbp + brow * 128 + GOFF(4 + lg, brow));
    const int ch = cc * 128 + brow;
#pragma unroll
    for (int m = 0; m < 4; ++m) {
      const int arow = m * 16 + lr;
      const bf16x8 a0 = *(const bf16x8*)(xa + arow * 128 + GOFF(lg, arow));
      const bf16x8 a1 = *(const bf16x8*)(xa + arow * 128 + GOFF(4 + lg, arow));
      f32x4 acc = {0.f, 0.f, 0.f, 0.f};
      acc = MFMA(a0, b0, acc);
      acc = MFMA(a1, b1, acc);
#pragma unroll
      for (int r = 0; r < 4; ++r) {
        const int s = m * 16 + lg * 4 + r;
        *(__bf16*)(act + s * 512 + GOFF(ch >> 3, s) + (ch & 7) * 2) =
            (__bf16)fast_tanh(acc[r] + bv1[cc]);
      }
    }
    __syncthreads();
  }

  // L2o: chunks 2-9 (32 ch each); m = wave>>1, n = wave&1
#pragma unroll
  for (int cc = 0; cc < 8; ++cc) {
    const int c = cc + 2;
    if (c + 1 < 10) stage_chunk2(Wc, wb, c + 1, wave);
    const char* wbp = wb + (c & 1) * 16384;
    const int m = wave >> 1, n = wave & 1;
    const int ch = cc * 32 + n * 16 + lr;
    const int brow = n * 16 + lr;
    const int arow = m * 16 + lr;
    f32x4 acc = {0.f, 0.f, 0.f, 0.f};
#pragma unroll
    for (int ks = 0; ks < 8; ++ks) {
      const int g = ks * 4 + lg;
      const bf16x8 a = *(const bf16x8*)(act + arow * 512 + GOFF(g, arow));
      const bf16x8 b = *(const bf16x8*)(wbp + brow * 512 + GOFF(g, brow));
      acc = MFMA(a, b, acc);
    }
#pragma unroll
    for (int r = 0; r < 4; ++r) {
      const int s = m * 16 + lg * 4 + r;
      g2[(size_t)(sb + s) * 256 + ch] = (__bf16)fast_tanh(acc[r] + bv2[cc]);
    }
    if (cc < 7) __syncthreads();
  }
}

// ---------------- diag_trunk: x -> tanh(Wd1) -> tanh(Wd2) -> Wdo -> xd ----------
// chunks: 0-1 = Wd1 (128B rows), 2-9 = Wd2, 10-11 = Wdo (512B rows)
__global__ __launch_bounds__(512, 2) void diag_trunk_kernel(
    const float* __restrict__ x, const __bf16* __restrict__ Wreg,
    const float* __restrict__ bd1, const float* __restrict__ bd2,
    const float* __restrict__ bdo, float* __restrict__ xd) {
  extern __shared__ char smem[];
  char* xa  = smem;            // 8 KB
  char* act = smem + 8192;     // 32 KB (h1, then h2)
  char* wb  = smem + 40960;    // 32 KB
  const char* Wc = (const char*)Wreg;

  const int tid = threadIdx.x;
  const int wave = tid >> 6, lane = tid & 63;
  const int lr = lane & 15, lg = lane >> 4;
  const int sb = blockIdx.x * 64;

  float bv1[2], bv2[8], bv3[2];
#pragma unroll
  for (int cc = 0; cc < 2; ++cc) bv1[cc] = bd1[cc * 128 + wave * 16 + lr];
#pragma unroll
  for (int cc = 0; cc < 8; ++cc) bv2[cc] = bd2[cc * 32 + (wave & 1) * 16 + lr];
#pragma unroll
  for (int cc = 0; cc < 2; ++cc) bv3[cc] = bdo[cc * 32 + (wave & 1) * 16 + lr];

  {
    const int s = tid >> 3, g = tid & 7;
    const bf16x8 v = cvt8(x + (size_t)(sb + s) * 64 + g * 8);
    *(bf16x8*)(xa + s * 128 + GOFF(g, s)) = v;
  }
  stage_chunk2(Wc, wb, 0, wave);
  __syncthreads();

  // L1d: chunks 0-1 -> h1 in act
#pragma unroll
  for (int cc = 0; cc < 2; ++cc) {
    stage_chunk2(Wc, wb, cc + 1, wave);
    const char* wbp = wb + (cc & 1) * 16384;
    const int brow = wave * 16 + lr;
    const bf16x8 b0 = *(const bf16x8*)(wbp + brow * 128 + GOFF(lg, brow));
    const bf16x8 b1 = *(const bf16x8*)(wbp + brow * 128 + GOFF(4 + lg, brow));
    const int ch = cc * 128 + brow;
#pragma unroll
    for (int m = 0; m < 4; ++m) {
      const int arow = m * 16 + lr;
      const bf16x8 a0 = *(const bf16x8*)(xa + arow * 128 + GOFF(lg, arow));
      const bf16x8 a1 = *(const bf16x8*)(xa + arow * 128 + GOFF(4 + lg, arow));
      f32x4 acc = {0.f, 0.f, 0.f, 0.f};
      acc = MFMA(a0, b0, acc);
      acc = MFMA(a1, b1, acc);
#pragma unroll
      for (int r = 0; r < 4; ++r) {
        const int s = m * 16 + lg * 4 + r;
        *(__bf16*)(act + s * 512 + GOFF(ch >> 3, s) + (ch & 7) * 2) =
            (__bf16)fast_tanh(acc[r] + bv1[cc]);
      }
    }
    __syncthreads();
  }

  // L2d: chunks 2-9; h2 held in registers (fully unrolled -> static indexing)
  f32x4 h2v[8];
#pragma unroll
  for (int cc = 0; cc < 8; ++cc) {
    const int c = cc + 2;
    if (c + 1 < 11) stage_chunk2(Wc, wb, c + 1, wave);  // stages up to chunk 10
    const char* wbp = wb + (c & 1) * 16384;
    const int m = wave >> 1, n = wave & 1;
    const int brow = n * 16 + lr;
    const int arow = m * 16 + lr;
    f32x4 acc = {0.f, 0.f, 0.f, 0.f};
#pragma unroll
    for (int ks = 0; ks < 8; ++ks) {
      const int g = ks * 4 + lg;
      const bf16x8 a = *(const bf16x8*)(act + arow * 512 + GOFF(g, arow));
      const bf16x8 b = *(const bf16x8*)(wbp + brow * 512 + GOFF(g, brow));
      acc = MFMA(a, b, acc);
    }
#pragma unroll
    for (int r = 0; r < 4; ++r) h2v[cc][r] = fast_tanh(acc[r] + bv2[cc]);
    __syncthreads();  // last one also certifies all h1 reads complete
  }

  // write h2 over h1; stage final chunk 11
  {
    const int m = wave >> 1, n = wave & 1;
#pragma unroll
    for (int cc = 0; cc < 8; ++cc) {
      const int ch = cc * 32 + n * 16 + lr;
#pragma unroll
      for (int r = 0; r < 4; ++r) {
        const int s = m * 16 + lg * 4 + r;
        *(__bf16*)(act + s * 512 + GOFF(ch >> 3, s) + (ch & 7) * 2) =
            (__bf16)h2v[cc][r];
      }
    }
  }
  stage_chunk2(Wc, wb, 11, wave);
  __syncthreads();

  // L3: chunks 10-11 (Wdo) -> xd f32, no tanh
#pragma unroll
  for (int cc = 0; cc < 2; ++cc) {
    const char* wbp = wb + ((10 + cc) & 1) * 16384;
    const int m = wave >> 1, n = wave & 1;
    const int ch = cc * 32 + n * 16 + lr;
    const int brow = n * 16 + lr;
    const int arow = m * 16 + lr;
    f32x4 acc = {0.f, 0.f, 0.f, 0.f};
#pragma unroll
    for (int ks = 0; ks < 8; ++ks) {
      const int g = ks * 4 + lg;
      const bf16x8 a = *(const bf16x8*)(act + arow * 512 + GOFF(g, arow));
      const bf16x8 b = *(const bf16x8*)(wbp + brow * 512 + GOFF(g, brow));
      acc = MFMA(a, b, acc);
    }
#pragma unroll
    for (int r = 0; r < 4; ++r) {
      const int s = m * 16 + lg * 4 + r;
      xd[(size_t)(sb + s) * 64 + ch] = acc[r] + bv3[cc];
    }
  }
}

// ---------------- gemm_z (round-10) + u32 paired-store epilogue -----------------
#define TILE_BYTES 32768
#define GEMM_SMEM  131072

__global__ __launch_bounds__(512, 2) void gemm_z_kernel(
    const __bf16* __restrict__ g2q, const __bf16* __restrict__ Woob,
    const float* __restrict__ boo, __bf16* __restrict__ zq) {
  extern __shared__ char gsm[];
  const int tid = threadIdx.x;
  const int wave = tid >> 6, lane = tid & 63;
  const int lr = lane & 15, lg = lane >> 4;
  const int bm = blockIdx.x & 31, bn = blockIdx.x >> 5;
  const int wr = wave >> 2, wc = wave & 3;
  const int srl = lane >> 3;
  const int sch = lane & 7;

#define STAGE(BUF, KT)                                                          \
  {                                                                             \
    _Pragma("unroll")                                                           \
    for (int j = 0; j < 4; ++j) {                                               \
      const int row = wave * 32 + j * 8 + srl;                                  \
      const int ka = (KT) * 64 + ((sch ^ (row & 7)) << 3);                      \
      gload_lds16(g2q + (size_t)(bm * 256 + row) * 256 + ka,                    \
                  gsm + (BUF) * TILE_BYTES + wave * 4096 + j * 1024);           \
      gload_lds16(Woob + (size_t)(bn * 256 + row) * 256 + ka,                   \
                  gsm + 65536 + (BUF) * TILE_BYTES + wave * 4096 + j * 1024);   \
    }                                                                           \
  }

  f32x4 acc[8][4];
#pragma unroll
  for (int i = 0; i < 8; ++i)
#pragma unroll
    for (int j = 0; j < 4; ++j) acc[i][j] = (f32x4){0.f, 0.f, 0.f, 0.f};

  STAGE(0, 0)
  __syncthreads();
#pragma unroll
  for (int kt = 0; kt < 4; ++kt) {
    if (kt < 3) STAGE((kt + 1) & 1, kt + 1)
    const __bf16* Ab = (const __bf16*)(gsm + (kt & 1) * TILE_BYTES);
    const __bf16* Bb = (const __bf16*)(gsm + 65536 + (kt & 1) * TILE_BYTES);
#pragma unroll
    for (int ks = 0; ks < 2; ++ks) {
      const int cc = ((ks * 4 + lg) ^ (lr & 7)) << 3;
      bf16x8 af[8];
#pragma unroll
      for (int fr = 0; fr < 8; ++fr)
        af[fr] = *(const bf16x8*)(Ab + (wr * 128 + fr * 16 + lr) * 64 + cc);
      bf16x8 bfr[4];
#pragma unroll
      for (int fc = 0; fc < 4; ++fc)
        bfr[fc] = *(const bf16x8*)(Bb + (wc * 64 + fc * 16 + lr) * 64 + cc);
#pragma unroll
      for (int fr = 0; fr < 8; ++fr)
#pragma unroll
        for (int fc = 0; fc < 4; ++fc)
          acc[fr][fc] = MFMA(af[fr], bfr[fc], acc[fr][fc]);
    }
    if (kt < 3) __syncthreads();
  }

  // epilogue: u32 paired stores into pair-interleaved padded triangle (+pads)
#pragma unroll
  for (int fc = 0; fc < 4; ++fc) {
    const int col = bn * 256 + wc * 64 + fc * 16 + lr;
    if (col < OFFD) {
      const float sq = sqrtf((float)(1 + 8 * col));
      const int i = (int)((1.f + sq) * 0.5f);
      const int tri = (i * (i - 1)) >> 1;
      const int r3i = i & 3;
      const int offv =
          tri + 6 * (i >> 2) + ((r3i == 2) ? 3 : (r3i == 3) ? 5 : 0) + (col - tri);
      const float bv = boo[col];
      const int pc = (4 - r3i) & 3;
      const bool lastcol = (col == tri + i - 1);
#pragma unroll
      for (int fr = 0; fr < 8; ++fr) {
#pragma unroll
        for (int h = 0; h < 2; ++h) {
          const int srow = bm * 256 + wr * 128 + fr * 16 + lg * 4 + h * 2;
          const int grp = srow >> 5, sig = srow & 31;  // sig even
          unsigned* p = (unsigned*)(zq + (size_t)grp * GRP_UNITS +
                                    (sig >> 1) * 4224 + (size_t)offv * 2);
          p[0] = bfbits(acc[fr][fc][h * 2] + bv) |
                 (bfbits(acc[fr][fc][h * 2 + 1] + bv) << 16);
          if (lastcol) {
#pragma unroll
            for (int d = 0; d < 3; ++d)
              if (d < pc) p[1 + d] = 0u;
          }
        }
      }
    }
  }
}

// ---------------- apply (round-10): wave-local stage + two triangular passes ----
#define APPLY_SMEM (GRP_BYTES + 8192)
__global__ __launch_bounds__(1024) void apply_kernel(
    const __bf16* __restrict__ zq, const float* __restrict__ xd,
    const float* __restrict__ x0, float* __restrict__ out, int s0base) {
  extern __shared__ char smem[];
  __bf16* ztb = (__bf16*)smem;
  float* ys2 = (float*)(smem + GRP_BYTES);

  const int tid = threadIdx.x;
  const int wave = tid >> 6, lane = tid & 63;
  const int sb = s0base + blockIdx.x * 32;
  const int s0 = wave * 2, s1 = s0 + 1;

  const float x0vA = x0[(size_t)(sb + s0) * 64 + lane];
  const float x0vB = x0[(size_t)(sb + s1) * 64 + lane];
  const float xdA = xd[(size_t)(sb + s0) * 64 + lane];
  const float xdB = xd[(size_t)(sb + s1) * 64 + lane];

  {
    const char* src = (const char*)zq + (size_t)blockIdx.x * GRP_BYTES + wave * 8448;
    char* dst = smem + wave * 8448;
#pragma unroll
    for (int j = 0; j < 8; ++j)
      gload_lds16(src + j * 1024 + lane * 16, dst + j * 1024);
    if (lane < 16) gload_lds16(src + 8192 + lane * 16, dst + 8192);
  }
  asm volatile("s_waitcnt vmcnt(0)" ::: "memory");
  SB0();

  const __bf16* zpair = ztb + wave * 4224;

  // pass 1: y_j = xd_j x0_j + sum_{k>j} z[k][j] x0_k  (one b32 = both samples)
  float yA = xdA * x0vA, yB = xdB * x0vB;
  int rs = 0;
#pragma unroll
  for (int k = 1; k < 64; ++k) {
    const unsigned w = *(const unsigned*)(zpair + (rs + lane) * 2);
    const float xkA = lane_bcast(x0vA, k);
    const float xkB = lane_bcast(x0vB, k);
    const bool mvalid = lane < k;
    yA += mvalid ? bf_lo(w) * xkA : 0.f;
    yB += mvalid ? bf_hi(w) * xkB : 0.f;
    rs += (k + 3) & ~3;
  }

  float* yp = ys2 + wave * 128;
  *(float2*)(yp + lane * 2) = make_float2(yA, yB);
  asm volatile("s_waitcnt lgkmcnt(0)" ::: "memory");
  SB0();

  // pass 2: D_i = xd_i y_i + sum_{j<i} z[i][j] y_j  (zero pads absorb masks)
  float DA = xdA * yA, DB = xdB * yB;
  float dA1 = 0.f, dB1 = 0.f;
  {
    const int r3 = lane & 3;
    const int rsi = ((lane * (lane - 1)) >> 1) + 6 * (lane >> 2) +
                    ((r3 == 2) ? 3 : (r3 == 3) ? 5 : 0);
    const int cmax = (lane + 3) >> 2;
    const __bf16* zrow = zpair + rsi * 2;
#pragma unroll 4
    for (int c = 0; c < cmax; ++c) {
      const uint4 w = *(const uint4*)(zrow + c * 8);
      const float4 u0 = *(const float4*)(yp + c * 8);
      const float4 u1 = *(const float4*)(yp + c * 8 + 4);
      DA += bf_lo(w.x) * u0.x + bf_lo(w.z) * u1.x;
      dA1 += bf_lo(w.y) * u0.z + bf_lo(w.w) * u1.z;
      DB += bf_hi(w.x) * u0.y + bf_hi(w.z) * u1.y;
      dB1 += bf_hi(w.y) * u0.w + bf_hi(w.w) * u1.w;
    }
  }
  out[(size_t)(sb + s0) * 64 + lane] = DA + dA1;
  out[(size_t)(sb + s1) * 64 + lane] = DB + dB1;
}

// ---------------- launch ----------------
extern "C" void kernel_launch(void* const* d_in, const int* in_sizes, int n_in,
                              void* d_out, int out_size, void* d_ws, size_t ws_size,
                              hipStream_t stream) {
  const float* x   = (const float*)d_in[0];
  const float* Wd1 = (const float*)d_in[1];
  const float* bd1 = (const float*)d_in[2];
  const float* Wd2 = (const float*)d_in[3];
  const float* bd2 = (const float*)d_in[4];
  const float* Wdo = (const float*)d_in[5];
  const float* bdo = (const float*)d_in[6];
  const float* Wo1 = (const float*)d_in[7];
  const float* bo1 = (const float*)d_in[8];
  const float* Wo2 = (const float*)d_in[9];
  const float* bo2 = (const float*)d_in[10];
  const float* Woo = (const float*)d_in[11];
  const float* boo = (const float*)d_in[12];
  float* out = (float*)d_out;

  char* ws = (char*)d_ws;
  // Wcat (bf16 elems): Wo1@0 | Wo2@16384 | Wd1@81920 | Wd2@98304 | Wdo@163840
  __bf16* Wcat = (__bf16*)(ws + 0);          //   360448 B
  __bf16* Woob = (__bf16*)(ws + 360448);     //  1048576 B (zero-padded rows)
  __bf16* g2   = (__bf16*)(ws + 1409024);    // 16777216 B
  float*  xdp  = (float*)(ws + 18186240);    //  8388608 B
  __bf16* zq   = (__bf16*)(ws + 26574848);   // 34603008 B (one quarter)

  cast_all_kernel<<<512, 256, 0, stream>>>(
      Wo1, Wcat, HDIM * NDIM,
      Wo2, Wcat + 16384, HDIM * HDIM,
      Wd1, Wcat + 81920, HDIM * NDIM,
      Wd2, Wcat + 98304, HDIM * HDIM,
      Wdo, Wcat + 163840, NDIM * HDIM,
      Woo, Woob, OFFD * HDIM,
      Woob + OFFD * HDIM, 32 * HDIM);

  hipFuncSetAttribute((const void*)off_trunk_kernel,
                      hipFuncAttributeMaxDynamicSharedMemorySize, TRK_SMEM);
  hipFuncSetAttribute((const void*)diag_trunk_kernel,
                      hipFuncAttributeMaxDynamicSharedMemorySize, TRK_SMEM);
  off_trunk_kernel<<<B_TOT / 64, 512, TRK_SMEM, stream>>>(
      x, Wcat, bo1, bo2, g2);
  diag_trunk_kernel<<<B_TOT / 64, 512, TRK_SMEM, stream>>>(
      x, Wcat + 81920, bd1, bd2, bdo, xdp);

  hipFuncSetAttribute((const void*)gemm_z_kernel,
                      hipFuncAttributeMaxDynamicSharedMemorySize, GEMM_SMEM);
  hipFuncSetAttribute((const void*)apply_kernel,
                      hipFuncAttributeMaxDynamicSharedMemorySize, APPLY_SMEM);
  for (int q = 0; q < 4; ++q) {
    gemm_z_kernel<<<(QS / 256) * 8, 512, GEMM_SMEM, stream>>>(
        g2 + (size_t)q * QS * HDIM, Woob, boo, zq);
    apply_kernel<<<QS / 32, 1024, APPLY_SMEM, stream>>>(zq, xdp, x, out, q * QS);
  }
}